// Round 2
// baseline (331.969 us; speedup 1.0000x reference)
//
#include <hip/hip_runtime.h>
#include <hip/hip_bf16.h>

typedef __bf16 bf16x8 __attribute__((ext_vector_type(8)));
typedef float floatx4 __attribute__((ext_vector_type(4)));

#define LDW 136  // LDS activation row stride (128 + 8 pad -> 2-way bank alias only)

// transposed-weight workspace layout (element offsets, bf16)
#define O_E1W2  0
#define O_E2W1  16384
#define O_E2W2  49152
#define O_E3W1  65536
#define O_E3W2  81920
#define O_E4W1  98304
#define O_E4W2  131072
#define O_DM2T0 147456
#define O_DM2T1 163840
#define O_DO1   180224
#define O_DO2   196608
#define WS_ELEMS 212992

// Transpose f32 weights w[k][n] (n=128 always) -> bf16 Wt[n][k] into ws.
__global__ void prep_kernel(
    const float* e1w2, const float* e2w1, const float* e2w2,
    const float* e3w1, const float* e3w2, const float* e4w1,
    const float* e4w2, const float* dmsg2, const float* dout1,
    const float* dout2, __hip_bfloat16* ws)
{
  int idx = blockIdx.x * 256 + threadIdx.x;
  const float* srcs[11] = {e1w2, e2w1, e2w2, e3w1, e3w2, e4w1, e4w2,
                           dmsg2, dmsg2 + 16384, dout1 + 384, dout2};
  const int Ks[11] = {128, 256, 128, 128, 128, 256, 128, 128, 128, 128, 128};
  int off = 0;
  for (int s = 0; s < 11; ++s) {
    int K = Ks[s];
    int sz = 128 * K;
    if (idx < off + sz) {
      int local = idx - off;
      int n = local / K, k = local % K;
      ws[idx] = __float2bfloat16(srcs[s][k * 128 + n]);
      return;
    }
    off += sz;
  }
}

__global__ __launch_bounds__(256, 2) void nri_fused(
    const float* __restrict__ x,
    const float* __restrict__ e1w1, const float* __restrict__ e1b1,
    const float* __restrict__ e1b2, const float* __restrict__ e2b1,
    const float* __restrict__ e2b2, const float* __restrict__ e3b1,
    const float* __restrict__ e3b2, const float* __restrict__ e4b1,
    const float* __restrict__ e4b2, const float* __restrict__ ew_out,
    const float* __restrict__ eb_out, const float* __restrict__ dmsg_w1,
    const float* __restrict__ dmsg_b1, const float* __restrict__ dmsg_b2,
    const float* __restrict__ dout_w1, const float* __restrict__ dout_b1,
    const float* __restrict__ dout_b2, const float* __restrict__ dout_w3,
    const float* __restrict__ dout_b3, const __bf16* __restrict__ wt,
    float* __restrict__ out)
{
  const int tid  = threadIdx.x;
  const int wave = tid >> 6;
  const int lane = tid & 63;
  const int nl   = lane & 15;
  const int quad = lane >> 4;
  const int gbase = blockIdx.x * 16;  // 16 graphs per workgroup -> 96 rows

  __shared__ __align__(16) __hip_bfloat16 bufA[96 * LDW];
  __shared__ __align__(16) __hip_bfloat16 bufB[96 * LDW];
  __shared__ float xs[288];    // x block [16][6][3] as f32
  __shared__ float rt[192];    // rel_type [96][2]
  __shared__ float wE1[512];   // e1w1[3*128] + e1b1[128]
  __shared__ float wOut[258];  // ew_out[128*2] + eb_out[2]
  __shared__ float wM1[1792];  // d_msg_w1[2][6][128] + d_msg_b1[2][128]
  __shared__ float wD1x[384];  // d_out_w1 rows 0..2
  __shared__ float wD3[387];   // d_out_w3[128*3] + d_out_b3[3]

  // ---- stage 0: stage small weights + x block into LDS (f32) ----
  for (int i = tid; i < 288; i += 256) xs[i] = x[gbase * 18 + i];
  for (int i = tid; i < 512; i += 256)
    wE1[i] = (i < 384 ? e1w1[i] : e1b1[i - 384]);
  for (int i = tid; i < 258; i += 256)
    wOut[i] = (i < 256 ? ew_out[i] : eb_out[i - 256]);
  for (int i = tid; i < 1792; i += 256) {
    int t = i / 896, l = i % 896;
    wM1[i] = (l < 768 ? dmsg_w1[t * 768 + l] : dmsg_b1[t * 128 + (l - 768)]);
  }
  for (int i = tid; i < 384; i += 256) wD1x[i] = dout_w1[i];
  for (int i = tid; i < 387; i += 256)
    wD3[i] = (i < 384 ? dout_w3[i] : dout_b3[i - 384]);
  __syncthreads();

  // ---- helpers ----
  auto zero = [&](floatx4 (&a)[6][2]) {
    floatx4 zv = {0.f, 0.f, 0.f, 0.f};
#pragma unroll
    for (int i = 0; i < 6; ++i) { a[i][0] = zv; a[i][1] = zv; }
  };

  // C[96x128] += A(LDS bf16, optional ring-recv row remap) @ Wt(global, [128][128])
  auto gemm128 = [&](floatx4 (&acc)[6][2], const __hip_bfloat16* in, bool recv,
                     const __bf16* w) {
    int rofs[6];
#pragma unroll
    for (int mt = 0; mt < 6; ++mt) {
      int r = mt * 16 + nl;
      if (recv) { int e = r % 6; r += (e == 5) ? -5 : 1; }
      rofs[mt] = r * LDW;
    }
    const __bf16* ab = (const __bf16*)(const void*)in;
    const __bf16* w0 = w + (wave * 32 + nl) * 128 + quad * 8;
    const __bf16* w1 = w0 + 16 * 128;
#pragma unroll
    for (int ks = 0; ks < 4; ++ks) {
      int kk = ks * 32 + quad * 8;
      bf16x8 b0 = *(const bf16x8*)(w0 + ks * 32);
      bf16x8 b1 = *(const bf16x8*)(w1 + ks * 32);
#pragma unroll
      for (int mt = 0; mt < 6; ++mt) {
        bf16x8 a = *(const bf16x8*)(ab + rofs[mt] + kk);
        acc[mt][0] = __builtin_amdgcn_mfma_f32_16x16x32_bf16(a, b0, acc[mt][0], 0, 0, 0);
        acc[mt][1] = __builtin_amdgcn_mfma_f32_16x16x32_bf16(a, b1, acc[mt][1], 0, 0, 0);
      }
    }
  };

  // K=256 concat GEMM: k<128 from in0 (optional recv remap), k>=128 from in1 (self rows)
  auto gemm256 = [&](floatx4 (&acc)[6][2], const __hip_bfloat16* in0, bool recv0,
                     const __hip_bfloat16* in1, const __bf16* w) {
    int rofs0[6], rofs1[6];
#pragma unroll
    for (int mt = 0; mt < 6; ++mt) {
      int r = mt * 16 + nl;
      rofs1[mt] = r * LDW;
      if (recv0) { int e = r % 6; r += (e == 5) ? -5 : 1; }
      rofs0[mt] = r * LDW;
    }
    const __bf16* ab0 = (const __bf16*)(const void*)in0;
    const __bf16* ab1 = (const __bf16*)(const void*)in1;
    const __bf16* w0 = w + (wave * 32 + nl) * 256 + quad * 8;
    const __bf16* w1 = w0 + 16 * 256;
#pragma unroll
    for (int ks = 0; ks < 8; ++ks) {
      int kk = (ks & 3) * 32 + quad * 8;
      const __bf16* ab = (ks < 4) ? ab0 : ab1;
      const int* rofs = (ks < 4) ? rofs0 : rofs1;
      bf16x8 b0 = *(const bf16x8*)(w0 + ks * 32);
      bf16x8 b1 = *(const bf16x8*)(w1 + ks * 32);
#pragma unroll
      for (int mt = 0; mt < 6; ++mt) {
        bf16x8 a = *(const bf16x8*)(ab + rofs[mt] + kk);
        acc[mt][0] = __builtin_amdgcn_mfma_f32_16x16x32_bf16(a, b0, acc[mt][0], 0, 0, 0);
        acc[mt][1] = __builtin_amdgcn_mfma_f32_16x16x32_bf16(a, b1, acc[mt][1], 0, 0, 0);
      }
    }
  };

  // bias + activation (0 none, 1 elu, 2 relu) + bf16 store
  auto store_act = [&](floatx4 (&acc)[6][2], const float* bias, int act,
                       __hip_bfloat16* ob) {
#pragma unroll
    for (int nt = 0; nt < 2; ++nt) {
      int col = wave * 32 + nt * 16 + nl;
      float bv = bias[col];
#pragma unroll
      for (int mt = 0; mt < 6; ++mt) {
#pragma unroll
        for (int r = 0; r < 4; ++r) {
          float z = acc[mt][nt][r] + bv;
          if (act == 1) z = (z > 0.f) ? z : (__expf(z) - 1.f);
          else if (act == 2) z = fmaxf(z, 0.f);
          int row = mt * 16 + quad * 4 + r;
          ob[row * LDW + col] = __float2bfloat16(z);
        }
      }
    }
  };

  floatx4 acc[6][2];

  // ---- stage 1 (VALU): h_hidden = ELU(x @ e1w1 + e1b1) -> bufA ----
  for (int i = 0; i < 48; ++i) {
    int o = i * 256 + tid;
    int row = o >> 7, col = o & 127;
    const float* xr = xs + row * 3;
    float z = wE1[384 + col] + xr[0] * wE1[col] + xr[1] * wE1[128 + col] + xr[2] * wE1[256 + col];
    z = (z > 0.f) ? z : (__expf(z) - 1.f);
    bufA[row * LDW + col] = __float2bfloat16(z);
  }
  __syncthreads();

  // ---- stage 2: h = ELU(bufA @ e1w2 + e1b2) -> bufB ----
  zero(acc); gemm128(acc, bufA, false, wt + O_E1W2);
  store_act(acc, e1b2, 1, bufB);
  __syncthreads();

  // ---- stage 3: he_hidden = ELU(concat(h[recv], h[send]) @ e2w1 + e2b1) -> bufA ----
  zero(acc); gemm256(acc, bufB, true, bufB, wt + O_E2W1);
  store_act(acc, e2b1, 1, bufA);
  __syncthreads();

  // ---- stage 4: he = ELU(bufA @ e2w2 + e2b2) -> bufB (bufB = he, keep) ----
  zero(acc); gemm128(acc, bufA, false, wt + O_E2W2);
  store_act(acc, e2b2, 1, bufB);
  __syncthreads();

  // ---- stage 5: h2_hidden = ELU(he @ e3w1 + e3b1) -> bufA ----
  zero(acc); gemm128(acc, bufB, false, wt + O_E3W1);
  store_act(acc, e3b1, 1, bufA);
  __syncthreads();

  // ---- stage 6: h2 = ELU(bufA @ e3w2 + e3b2) -> bufA (in place, barrier between) ----
  zero(acc); gemm128(acc, bufA, false, wt + O_E3W2);
  __syncthreads();
  store_act(acc, e3b2, 1, bufA);
  __syncthreads();

  // ---- stage 7: h3_hidden = ELU(concat(h2, he) @ e4w1 + e4b1) -> bufA (in place) ----
  zero(acc); gemm256(acc, bufA, false, bufB, wt + O_E4W1);
  __syncthreads();
  store_act(acc, e4b1, 1, bufA);
  __syncthreads();

  // ---- stage 8: h3 = ELU(bufA @ e4w2 + e4b2) -> bufB ----
  zero(acc); gemm128(acc, bufA, false, wt + O_E4W2);
  store_act(acc, e4b2, 1, bufB);
  __syncthreads();

  // ---- stage 9 (VALU): logits -> softmax -> rt ----
  if (tid < 96) {
    float l0 = wOut[256], l1 = wOut[257];
    const __hip_bfloat16* hr = bufB + tid * LDW;
    for (int k = 0; k < 128; ++k) {
      float v = __bfloat162float(hr[k]);
      l0 += v * wOut[k * 2]; l1 += v * wOut[k * 2 + 1];
    }
    float mx = fmaxf(l0, l1);
    float ea = __expf(l0 - mx), eb = __expf(l1 - mx);
    float inv = 1.f / (ea + eb);
    rt[tid * 2] = ea * inv; rt[tid * 2 + 1] = eb * inv;
  }
  __syncthreads();

  // ---- decoder message passing: msg = sum_t rt[:,t] * relu(relu(pre_msg@w1_t+b1)@w2_t+b2) ----
  floatx4 msg[6][2];
  zero(msg);
  for (int t = 0; t < 2; ++t) {
    const float* wm = wM1 + t * 896;
    for (int i = 0; i < 48; ++i) {   // m1 (K=6, VALU) -> bufA
      int o = i * 256 + tid;
      int row = o >> 7, col = o & 127;
      int e = row % 6;
      int rrow = row + ((e == 5) ? -5 : 1);
      const float* xre = xs + rrow * 3;
      const float* xse = xs + row * 3;
      float z = wm[768 + col];
      z += xre[0] * wm[col] + xre[1] * wm[128 + col] + xre[2] * wm[256 + col];
      z += xse[0] * wm[384 + col] + xse[1] * wm[512 + col] + xse[2] * wm[640 + col];
      bufA[row * LDW + col] = __float2bfloat16(fmaxf(z, 0.f));
    }
    __syncthreads();
    zero(acc);
    gemm128(acc, bufA, false, wt + (t == 0 ? O_DM2T0 : O_DM2T1));
#pragma unroll
    for (int nt = 0; nt < 2; ++nt) {
      int col = wave * 32 + nt * 16 + nl;
      float bv = dmsg_b2[t * 128 + col];
#pragma unroll
      for (int mt = 0; mt < 6; ++mt)
#pragma unroll
        for (int r = 0; r < 4; ++r) {
          int row = mt * 16 + quad * 4 + r;
          float z = fmaxf(acc[mt][nt][r] + bv, 0.f);
          msg[mt][nt][r] += rt[row * 2 + t] * z;
        }
    }
    __syncthreads();
  }

  // ---- stage 12: agg_msgs (edge e -> node (e+1)%6) -> bufB ----
#pragma unroll
  for (int nt = 0; nt < 2; ++nt) {
    int col = wave * 32 + nt * 16 + nl;
#pragma unroll
    for (int mt = 0; mt < 6; ++mt)
#pragma unroll
      for (int r = 0; r < 4; ++r) {
        int row = mt * 16 + quad * 4 + r;
        int e = row % 6;
        int orow = row + ((e == 5) ? -5 : 1);
        bufB[orow * LDW + col] = __float2bfloat16(msg[mt][nt][r]);
      }
  }
  __syncthreads();

  // ---- stage 13: p1 = relu(concat(x, agg) @ d_out_w1 + b1) -> bufA (K=128 MFMA + K=3 VALU) ----
  zero(acc);
  gemm128(acc, bufB, false, wt + O_DO1);
#pragma unroll
  for (int nt = 0; nt < 2; ++nt) {
    int col = wave * 32 + nt * 16 + nl;
    float bv = dout_b1[col];
    float w0 = wD1x[col], w1 = wD1x[128 + col], w2 = wD1x[256 + col];
#pragma unroll
    for (int mt = 0; mt < 6; ++mt)
#pragma unroll
      for (int r = 0; r < 4; ++r) {
        int row = mt * 16 + quad * 4 + r;
        const float* xv = xs + row * 3;
        float z = acc[mt][nt][r] + bv + xv[0] * w0 + xv[1] * w1 + xv[2] * w2;
        bufA[row * LDW + col] = __float2bfloat16(fmaxf(z, 0.f));
      }
  }
  __syncthreads();

  // ---- stage 14: p2 = relu(bufA @ d_out_w2 + b2) -> bufB ----
  zero(acc); gemm128(acc, bufA, false, wt + O_DO2);
  store_act(acc, dout_b2, 2, bufB);
  __syncthreads();

  // ---- stage 15 (VALU): out = x + p2 @ d_out_w3 + b3 ----
  if (tid < 96) {
    float d0 = wD3[384], d1 = wD3[385], d2 = wD3[386];
    const __hip_bfloat16* pr = bufB + tid * LDW;
    for (int k = 0; k < 128; ++k) {
      float v = __bfloat162float(pr[k]);
      d0 += v * wD3[k * 3]; d1 += v * wD3[k * 3 + 1]; d2 += v * wD3[k * 3 + 2];
    }
    int ob = gbase * 18 + tid * 3;
    out[ob]     = xs[tid * 3]     + d0;
    out[ob + 1] = xs[tid * 3 + 1] + d1;
    out[ob + 2] = xs[tid * 3 + 2] + d2;
  }
}

extern "C" void kernel_launch(void* const* d_in, const int* in_sizes, int n_in,
                              void* d_out, int out_size, void* d_ws, size_t ws_size,
                              hipStream_t stream) {
  const float* x       = (const float*)d_in[0];
  const float* e1w1    = (const float*)d_in[3];
  const float* e1b1    = (const float*)d_in[4];
  const float* e1w2    = (const float*)d_in[5];
  const float* e1b2    = (const float*)d_in[6];
  const float* e2w1    = (const float*)d_in[7];
  const float* e2b1    = (const float*)d_in[8];
  const float* e2w2    = (const float*)d_in[9];
  const float* e2b2    = (const float*)d_in[10];
  const float* e3w1    = (const float*)d_in[11];
  const float* e3b1    = (const float*)d_in[12];
  const float* e3w2    = (const float*)d_in[13];
  const float* e3b2    = (const float*)d_in[14];
  const float* e4w1    = (const float*)d_in[15];
  const float* e4b1    = (const float*)d_in[16];
  const float* e4w2    = (const float*)d_in[17];
  const float* e4b2    = (const float*)d_in[18];
  const float* ew_out  = (const float*)d_in[19];
  const float* eb_out  = (const float*)d_in[20];
  const float* dmsg_w1 = (const float*)d_in[21];
  const float* dmsg_b1 = (const float*)d_in[22];
  const float* dmsg_w2 = (const float*)d_in[23];
  const float* dmsg_b2 = (const float*)d_in[24];
  const float* dout_w1 = (const float*)d_in[25];
  const float* dout_b1 = (const float*)d_in[26];
  const float* dout_w2 = (const float*)d_in[27];
  const float* dout_b2 = (const float*)d_in[28];
  const float* dout_w3 = (const float*)d_in[29];
  const float* dout_b3 = (const float*)d_in[30];

  prep_kernel<<<(WS_ELEMS + 255) / 256, 256, 0, stream>>>(
      e1w2, e2w1, e2w2, e3w1, e3w2, e4w1, e4w2, dmsg_w2, dout_w1, dout_w2,
      (__hip_bfloat16*)d_ws);

  nri_fused<<<32768 / 16, 256, 0, stream>>>(
      x, e1w1, e1b1, e1b2, e2b1, e2b2, e3b1, e3b2, e4b1, e4b2,
      ew_out, eb_out, dmsg_w1, dmsg_b1, dmsg_b2,
      dout_w1, dout_b1, dout_b2, dout_w3, dout_b3,
      (const __bf16*)d_ws, (float*)d_out);
}